// Round 1
// baseline (424.931 us; speedup 1.0000x reference)
//
#include <hip/hip_runtime.h>

#define B_ 4
#define C_ 64
#define H_ 256
#define W_ 256
#define KK 9

// ---------------- Kernel 1: 5x5 conv (C=64 -> 9), pad=2, + bias, tanh ----------------
// One thread per output pixel (all 9 output channels in registers).
// Input staged in LDS 8 channels at a time; weights read wave-uniform (-> SGPR loads).
__global__ __launch_bounds__(256) void conv5_tanh(
    const float* __restrict__ x, const float* __restrict__ w,
    const float* __restrict__ bias, float* __restrict__ out)
{
    const int TW = 32, TH = 8;
    const int PW = TW + 4, PH = TH + 4; // 36, 12
    __shared__ float lds[8][PH][PW];

    int tid = threadIdx.x;
    int tx = tid & 31, ty = tid >> 5;
    int bw = blockIdx.x & 7;          // W/TW = 8
    int bh = (blockIdx.x >> 3) & 31;  // H/TH = 32
    int b  = blockIdx.x >> 8;         // 0..3
    int h0 = bh * TH, w0 = bw * TW;

    float acc[KK];
    #pragma unroll
    for (int j = 0; j < KK; ++j) acc[j] = bias[j];

    for (int c0 = 0; c0 < C_; c0 += 8) {
        __syncthreads();
        for (int idx = tid; idx < 8 * PH * PW; idx += 256) {
            int px = idx % PW;
            int py = (idx / PW) % PH;
            int ch = idx / (PW * PH);
            int gy = h0 + py - 2;
            int gx = w0 + px - 2;
            float v = 0.f;
            if (gy >= 0 && gy < H_ && gx >= 0 && gx < W_)
                v = x[((b * C_ + c0 + ch) * H_ + gy) * W_ + gx];
            lds[ch][py][px] = v;
        }
        __syncthreads();
        for (int ch = 0; ch < 8; ++ch) {
            int c = c0 + ch;
            #pragma unroll
            for (int di = 0; di < 5; ++di) {
                #pragma unroll
                for (int dj = 0; dj < 5; ++dj) {
                    float xv = lds[ch][ty + di][tx + dj];
                    #pragma unroll
                    for (int j = 0; j < KK; ++j)
                        acc[j] += xv * w[((j * C_ + c) * 5 + di) * 5 + dj];
                }
            }
        }
    }
    int h = h0 + ty, wq = w0 + tx;
    #pragma unroll
    for (int j = 0; j < KK; ++j)
        out[((b * KK + j) * H_ + h) * W_ + wq] = tanhf(acc[j]);
}

// ---------------- Kernel 2: per-pixel dynamic 3x3 filter ----------------
// out_attf[b,c,h,w] = sum_{di,dj} x[b,c,h+di-1,w+dj-1] * att[b,di*3+dj,h,w]
__global__ __launch_bounds__(256) void perpix(
    const float* __restrict__ x, const float* __restrict__ att,
    float* __restrict__ attf)
{
    int idx = blockIdx.x * 256 + threadIdx.x; // over B*C*H*W = 2^24
    int wq = idx & (W_ - 1);
    int h  = (idx >> 8) & (H_ - 1);
    int b  = idx >> 22;

    float a[KK];
    #pragma unroll
    for (int j = 0; j < KK; ++j)
        a[j] = att[((b * KK + j) * H_ + h) * W_ + wq];

    float s = 0.f;
    #pragma unroll
    for (int di = 0; di < 3; ++di) {
        int y = h + di - 1;
        if (y < 0 || y >= H_) continue;
        #pragma unroll
        for (int dj = 0; dj < 3; ++dj) {
            int xq = wq + dj - 1;
            if (xq < 0 || xq >= W_) continue;
            s += x[(idx & ~(H_ * W_ - 1)) + y * W_ + xq] * a[di * 3 + dj];
        }
    }
    attf[idx] = s;
}

// ---------------- Kernel 3: 3x3 conv (C=64 -> 9) on (x - attf), pad=1, + bias ----------------
__global__ __launch_bounds__(256) void conv3_diff(
    const float* __restrict__ x, const float* __restrict__ attf,
    const float* __restrict__ w, const float* __restrict__ bias,
    float* __restrict__ out)
{
    const int TW = 32, TH = 8;
    const int PW = TW + 2, PH = TH + 2; // 34, 10
    __shared__ float lds[8][PH][PW];

    int tid = threadIdx.x;
    int tx = tid & 31, ty = tid >> 5;
    int bw = blockIdx.x & 7;
    int bh = (blockIdx.x >> 3) & 31;
    int b  = blockIdx.x >> 8;
    int h0 = bh * TH, w0 = bw * TW;

    float acc[KK];
    #pragma unroll
    for (int j = 0; j < KK; ++j) acc[j] = bias[j];

    for (int c0 = 0; c0 < C_; c0 += 8) {
        __syncthreads();
        for (int idx = tid; idx < 8 * PH * PW; idx += 256) {
            int px = idx % PW;
            int py = (idx / PW) % PH;
            int ch = idx / (PW * PH);
            int gy = h0 + py - 1;
            int gx = w0 + px - 1;
            float v = 0.f;
            if (gy >= 0 && gy < H_ && gx >= 0 && gx < W_) {
                int gi = ((b * C_ + c0 + ch) * H_ + gy) * W_ + gx;
                v = x[gi] - attf[gi];
            }
            lds[ch][py][px] = v;
        }
        __syncthreads();
        for (int ch = 0; ch < 8; ++ch) {
            int c = c0 + ch;
            #pragma unroll
            for (int di = 0; di < 3; ++di) {
                #pragma unroll
                for (int dj = 0; dj < 3; ++dj) {
                    float xv = lds[ch][ty + di][tx + dj];
                    #pragma unroll
                    for (int j = 0; j < KK; ++j)
                        acc[j] += xv * w[((j * C_ + c) * 3 + di) * 3 + dj];
                }
            }
        }
    }
    int h = h0 + ty, wq = w0 + tx;
    #pragma unroll
    for (int j = 0; j < KK; ++j)
        out[((b * KK + j) * H_ + h) * W_ + wq] = acc[j];
}

// ---------------- Kernel 4: 3x3 conv (9 -> 9), pad=1, + bias, tanh ----------------
// One thread per spatial pixel; all 9 in-ch x 9 out-ch in registers; weights uniform.
__global__ __launch_bounds__(256) void conv3_tanh(
    const float* __restrict__ r1, const float* __restrict__ w,
    const float* __restrict__ bias, float* __restrict__ out)
{
    int idx = blockIdx.x * 256 + threadIdx.x; // over B*H*W = 262144
    int wq = idx & (W_ - 1);
    int h  = (idx >> 8) & (H_ - 1);
    int b  = idx >> 16;

    float acc[KK];
    #pragma unroll
    for (int j = 0; j < KK; ++j) acc[j] = bias[j];

    for (int cin = 0; cin < KK; ++cin) {
        #pragma unroll
        for (int di = 0; di < 3; ++di) {
            int y = h + di - 1;
            if (y < 0 || y >= H_) continue;
            #pragma unroll
            for (int dj = 0; dj < 3; ++dj) {
                int xq = wq + dj - 1;
                if (xq < 0 || xq >= W_) continue;
                float xv = r1[((b * KK + cin) * H_ + y) * W_ + xq];
                #pragma unroll
                for (int j = 0; j < KK; ++j)
                    acc[j] += xv * w[((j * KK + cin) * 3 + di) * 3 + dj];
            }
        }
    }
    #pragma unroll
    for (int j = 0; j < KK; ++j)
        out[((b * KK + j) * H_ + h) * W_ + wq] = tanhf(acc[j]);
}

extern "C" void kernel_launch(void* const* d_in, const int* in_sizes, int n_in,
                              void* d_out, int out_size, void* d_ws, size_t ws_size,
                              hipStream_t stream) {
    const float* feature = (const float*)d_in[0];
    const float* w_sharp = (const float*)d_in[1];
    const float* b_sharp = (const float*)d_in[2];
    const float* w_r1    = (const float*)d_in[3];
    const float* b_r1    = (const float*)d_in[4];
    const float* w_r2    = (const float*)d_in[5];
    const float* b_r2    = (const float*)d_in[6];

    float* out_reblur = (float*)d_out;                         // [4,9,256,256]
    float* out_attf   = out_reblur + (size_t)B_ * KK * H_ * W_; // [4,64,256,256]

    float* ws_att = (float*)d_ws;                               // [4,9,256,256]
    float* ws_r1  = ws_att + (size_t)B_ * KK * H_ * W_;         // [4,9,256,256]

    conv5_tanh<<<1024, 256, 0, stream>>>(feature, w_sharp, b_sharp, ws_att);
    perpix<<<65536, 256, 0, stream>>>(feature, ws_att, out_attf);
    conv3_diff<<<1024, 256, 0, stream>>>(feature, out_attf, w_r1, b_r1, ws_r1);
    conv3_tanh<<<1024, 256, 0, stream>>>(ws_r1, w_r2, b_r2, out_reblur);
}

// Round 2
// 275.504 us; speedup vs baseline: 1.5424x; 1.5424x over previous
//
#include <hip/hip_runtime.h>

#define B_ 4
#define C_ 64
#define H_ 256
#define W_ 256
#define KK 9

typedef __attribute__((ext_vector_type(8))) short short8;
typedef __attribute__((ext_vector_type(4))) float float4_;

static __device__ __forceinline__ unsigned short f2bf(float f) {
    unsigned int u = __builtin_bit_cast(unsigned int, f);
    unsigned int r = (u + 0x7fffu + ((u >> 16) & 1u)) >> 16;  // RNE
    return (unsigned short)r;
}

// ---------------- Kernel A: NCHW fp32 -> NHWC bf16 ----------------
// 8 threads per pixel, each converting 8 channels. Writes fully coalesced.
__global__ __launch_bounds__(256) void nchw2nhwc(
    const float* __restrict__ x, unsigned short* __restrict__ xh)
{
    int t = blockIdx.x * 256 + threadIdx.x;   // B*H*W*8 = 2097152
    int g = t & 7;
    int pix = t >> 3;                         // b*65536 + hw
    int b = pix >> 16;
    int hw = pix & 65535;
    const float* src = x + (size_t)(b * 64 + g * 8) * 65536 + hw;
    short8 v;
    #pragma unroll
    for (int i = 0; i < 8; ++i)
        v[i] = (short)f2bf(src[(size_t)i * 65536]);
    *(short8*)(xh + (size_t)pix * 64 + g * 8) = v;
}

// ---------------- Kernel B: weight transform ----------------
// w_sharp [9][64][5][5] f32 -> wb [25 tap][8 q][16 n][8 e] bf16 (c = q*8+e, n>=9 zero)
__global__ __launch_bounds__(256) void wprep(
    const float* __restrict__ w, unsigned short* __restrict__ wb)
{
    int i = blockIdx.x * 256 + threadIdx.x;   // 25*8*16*8 = 25600
    if (i >= 25600) return;
    int tap = i >> 10;
    int q = (i >> 7) & 7;
    int n = (i >> 3) & 15;
    int e = i & 7;
    int c = q * 8 + e;
    int di = tap / 5, dj = tap % 5;
    float v = (n < KK) ? w[((n * C_ + c) * 5 + di) * 5 + dj] : 0.f;
    wb[i] = f2bf(v);
}

// ---------------- Kernel C: conv5 + tanh via bf16 MFMA ----------------
// Tap-loop implicit GEMM: per tap (di,dj), Y[16pix x 9] += A[16pix x 64ch] * B[64 x 9]
#define PADC 72   // per-pixel channel stride in LDS (bf16): breaks bank conflicts
__global__ __launch_bounds__(256) void conv5_mfma(
    const unsigned short* __restrict__ xh,   // [B][H][W][64] bf16
    const unsigned short* __restrict__ wb,   // [25][8][16][8] bf16
    const float* __restrict__ bias,
    float* __restrict__ out)                 // [B][9][H][W] f32 (tanh applied)
{
    __shared__ unsigned short xs[20 * 20 * PADC];  // 57600 B

    int tid = threadIdx.x;
    int bx = blockIdx.x & 15;
    int by = (blockIdx.x >> 4) & 15;
    int b  = blockIdx.x >> 8;
    int h0 = by * 16, w0 = bx * 16;

    // stage 20x20 pixels x 64 ch (halo 2, zero-padded) as 16B chunks
    for (int q = tid; q < 400 * 8; q += 256) {
        int p = q & 7;
        int pix = q >> 3;
        int py = pix / 20, px = pix % 20;
        int gy = h0 + py - 2, gx = w0 + px - 2;
        short8 v = (short8)0;
        if (gy >= 0 && gy < H_ && gx >= 0 && gx < W_)
            v = *(const short8*)(xh + ((size_t)((b * 256 + gy) * 256 + gx) * 64 + p * 8));
        *(short8*)(&xs[pix * PADC + p * 8]) = v;
    }
    __syncthreads();

    int lane = tid & 63;
    int wid  = tid >> 6;      // 4 waves, each owns 4 pixel rows
    int m16  = lane & 15;     // A row (px) and B col (out channel j)
    int lq   = lane >> 4;     // 0..3: k-group

    float4_ acc[4];
    float bj = (m16 < KK) ? bias[m16] : 0.f;
    #pragma unroll
    for (int r = 0; r < 4; ++r) acc[r] = (float4_){bj, bj, bj, bj};

    #pragma unroll
    for (int di = 0; di < 5; ++di) {
        #pragma unroll
        for (int dj = 0; dj < 5; ++dj) {
            int tap = di * 5 + dj;
            // B frags (k = 0..31 and 32..63): lane provides B[k=(lq*8+e)+32*kb][n=m16]
            short8 bf0 = *(const short8*)(wb + (((tap * 8 + lq) * 16 + m16) * 8));
            short8 bf1 = *(const short8*)(wb + (((tap * 8 + 4 + lq) * 16 + m16) * 8));
            #pragma unroll
            for (int r = 0; r < 4; ++r) {
                int py = wid * 4 + r + di;      // 0..19
                int px = m16 + dj;              // 0..19
                const unsigned short* base = &xs[(py * 20 + px) * PADC + lq * 8];
                short8 a0 = *(const short8*)(base);
                short8 a1 = *(const short8*)(base + 32);
                acc[r] = __builtin_amdgcn_mfma_f32_16x16x32_bf16(a0, bf0, acc[r], 0, 0, 0);
                acc[r] = __builtin_amdgcn_mfma_f32_16x16x32_bf16(a1, bf1, acc[r], 0, 0, 0);
            }
        }
    }

    // D layout: n = lane&15, m(px) = (lane>>4)*4 + reg
    if (m16 < KK) {
        #pragma unroll
        for (int r = 0; r < 4; ++r) {
            int py = h0 + wid * 4 + r;
            #pragma unroll
            for (int reg = 0; reg < 4; ++reg) {
                int px = w0 + lq * 4 + reg;
                out[((b * KK + m16) * H_ + py) * W_ + px] = tanhf(acc[r][reg]);
            }
        }
    }
}

// ---------------- Kernel 2: per-pixel dynamic 3x3 filter (unchanged) ----------------
__global__ __launch_bounds__(256) void perpix(
    const float* __restrict__ x, const float* __restrict__ att,
    float* __restrict__ attf)
{
    int idx = blockIdx.x * 256 + threadIdx.x;
    int wq = idx & (W_ - 1);
    int h  = (idx >> 8) & (H_ - 1);
    int b  = idx >> 22;

    float a[KK];
    #pragma unroll
    for (int j = 0; j < KK; ++j)
        a[j] = att[((b * KK + j) * H_ + h) * W_ + wq];

    float s = 0.f;
    #pragma unroll
    for (int di = 0; di < 3; ++di) {
        int y = h + di - 1;
        if (y < 0 || y >= H_) continue;
        #pragma unroll
        for (int dj = 0; dj < 3; ++dj) {
            int xq = wq + dj - 1;
            if (xq < 0 || xq >= W_) continue;
            s += x[(idx & ~(H_ * W_ - 1)) + y * W_ + xq] * a[di * 3 + dj];
        }
    }
    attf[idx] = s;
}

// ---------------- Kernel 3: 3x3 conv (C=64 -> 9) on (x - attf) (unchanged) ----------------
__global__ __launch_bounds__(256) void conv3_diff(
    const float* __restrict__ x, const float* __restrict__ attf,
    const float* __restrict__ w, const float* __restrict__ bias,
    float* __restrict__ out)
{
    const int TW = 32, TH = 8;
    const int PW = TW + 2, PH = TH + 2;
    __shared__ float lds[8][PH][PW];

    int tid = threadIdx.x;
    int tx = tid & 31, ty = tid >> 5;
    int bw = blockIdx.x & 7;
    int bh = (blockIdx.x >> 3) & 31;
    int b  = blockIdx.x >> 8;
    int h0 = bh * TH, w0 = bw * TW;

    float acc[KK];
    #pragma unroll
    for (int j = 0; j < KK; ++j) acc[j] = bias[j];

    for (int c0 = 0; c0 < C_; c0 += 8) {
        __syncthreads();
        for (int idx = tid; idx < 8 * PH * PW; idx += 256) {
            int px = idx % PW;
            int py = (idx / PW) % PH;
            int ch = idx / (PW * PH);
            int gy = h0 + py - 1;
            int gx = w0 + px - 1;
            float v = 0.f;
            if (gy >= 0 && gy < H_ && gx >= 0 && gx < W_) {
                int gi = ((b * C_ + c0 + ch) * H_ + gy) * W_ + gx;
                v = x[gi] - attf[gi];
            }
            lds[ch][py][px] = v;
        }
        __syncthreads();
        for (int ch = 0; ch < 8; ++ch) {
            int c = c0 + ch;
            #pragma unroll
            for (int di = 0; di < 3; ++di) {
                #pragma unroll
                for (int dj = 0; dj < 3; ++dj) {
                    float xv = lds[ch][ty + di][tx + dj];
                    #pragma unroll
                    for (int j = 0; j < KK; ++j)
                        acc[j] += xv * w[((j * C_ + c) * 3 + di) * 3 + dj];
                }
            }
        }
    }
    int h = h0 + ty, wq = w0 + tx;
    #pragma unroll
    for (int j = 0; j < KK; ++j)
        out[((b * KK + j) * H_ + h) * W_ + wq] = acc[j];
}

// ---------------- Kernel 4: 3x3 conv (9 -> 9) + tanh (unchanged) ----------------
__global__ __launch_bounds__(256) void conv3_tanh(
    const float* __restrict__ r1, const float* __restrict__ w,
    const float* __restrict__ bias, float* __restrict__ out)
{
    int idx = blockIdx.x * 256 + threadIdx.x;
    int wq = idx & (W_ - 1);
    int h  = (idx >> 8) & (H_ - 1);
    int b  = idx >> 16;

    float acc[KK];
    #pragma unroll
    for (int j = 0; j < KK; ++j) acc[j] = bias[j];

    for (int cin = 0; cin < KK; ++cin) {
        #pragma unroll
        for (int di = 0; di < 3; ++di) {
            int y = h + di - 1;
            if (y < 0 || y >= H_) continue;
            #pragma unroll
            for (int dj = 0; dj < 3; ++dj) {
                int xq = wq + dj - 1;
                if (xq < 0 || xq >= W_) continue;
                float xv = r1[((b * KK + cin) * H_ + y) * W_ + xq];
                #pragma unroll
                for (int j = 0; j < KK; ++j)
                    acc[j] += xv * w[((j * KK + cin) * 3 + di) * 3 + dj];
            }
        }
    }
    #pragma unroll
    for (int j = 0; j < KK; ++j)
        out[((b * KK + j) * H_ + h) * W_ + wq] = tanhf(acc[j]);
}

extern "C" void kernel_launch(void* const* d_in, const int* in_sizes, int n_in,
                              void* d_out, int out_size, void* d_ws, size_t ws_size,
                              hipStream_t stream) {
    const float* feature = (const float*)d_in[0];
    const float* w_sharp = (const float*)d_in[1];
    const float* b_sharp = (const float*)d_in[2];
    const float* w_r1    = (const float*)d_in[3];
    const float* b_r1    = (const float*)d_in[4];
    const float* w_r2    = (const float*)d_in[5];
    const float* b_r2    = (const float*)d_in[6];

    float* out_reblur = (float*)d_out;                          // [4,9,256,256]
    float* out_attf   = out_reblur + (size_t)B_ * KK * H_ * W_; // [4,64,256,256]

    char* ws = (char*)d_ws;
    unsigned short* xh = (unsigned short*)ws;                    // 33554432 B
    unsigned short* wb = (unsigned short*)(ws + 33554432);       // 51200 B (pad to 64K)
    float* ws_att = (float*)(ws + 33554432 + 65536);             // 9437184 B
    float* ws_r1  = (float*)(ws + 33554432 + 65536 + 9437184);   // 9437184 B

    nchw2nhwc<<<8192, 256, 0, stream>>>(feature, xh);
    wprep<<<100, 256, 0, stream>>>(w_sharp, wb);
    conv5_mfma<<<1024, 256, 0, stream>>>(xh, wb, b_sharp, ws_att);
    perpix<<<65536, 256, 0, stream>>>(feature, ws_att, out_attf);
    conv3_diff<<<1024, 256, 0, stream>>>(feature, out_attf, w_r1, b_r1, ws_r1);
    conv3_tanh<<<1024, 256, 0, stream>>>(ws_r1, w_r2, b_r2, out_reblur);
}

// Round 3
// 135.773 us; speedup vs baseline: 3.1297x; 2.0291x over previous
//
#include <hip/hip_runtime.h>

#define B_ 4
#define C_ 64
#define H_ 256
#define W_ 256
#define KK 9

typedef __attribute__((ext_vector_type(8))) short short8;
typedef __attribute__((ext_vector_type(4))) float float4_;

static __device__ __forceinline__ unsigned short f2bf(float f) {
    unsigned int u = __builtin_bit_cast(unsigned int, f);
    unsigned int r = (u + 0x7fffu + ((u >> 16) & 1u)) >> 16;  // RNE
    return (unsigned short)r;
}
static __device__ __forceinline__ float bf2f(short s) {
    return __builtin_bit_cast(float, (unsigned int)((unsigned short)s) << 16);
}

// ---------------- Kernel A: NCHW fp32 -> NHWC bf16 ----------------
__global__ __launch_bounds__(256) void nchw2nhwc(
    const float* __restrict__ x, unsigned short* __restrict__ xh)
{
    int t = blockIdx.x * 256 + threadIdx.x;   // B*H*W*8 = 2097152
    int g = t & 7;
    int pix = t >> 3;                         // b*65536 + hw
    int b = pix >> 16;
    int hw = pix & 65535;
    const float* src = x + (size_t)(b * 64 + g * 8) * 65536 + hw;
    short8 v;
    #pragma unroll
    for (int i = 0; i < 8; ++i)
        v[i] = (short)f2bf(src[(size_t)i * 65536]);
    *(short8*)(xh + (size_t)pix * 64 + g * 8) = v;
}

// ---------------- Kernel B: 5x5 weight transform ----------------
// w_sharp [9][64][5][5] f32 -> wb [25 tap][8 q][16 n][8 e] bf16 (c = q*8+e)
__global__ __launch_bounds__(256) void wprep(
    const float* __restrict__ w, unsigned short* __restrict__ wb)
{
    int i = blockIdx.x * 256 + threadIdx.x;   // 25600
    if (i >= 25600) return;
    int tap = i >> 10;
    int q = (i >> 7) & 7;
    int n = (i >> 3) & 15;
    int e = i & 7;
    int c = q * 8 + e;
    int di = tap / 5, dj = tap % 5;
    float v = (n < KK) ? w[((n * C_ + c) * 5 + di) * 5 + dj] : 0.f;
    wb[i] = f2bf(v);
}

// ---------------- Kernel B2: 3x3 weight transform ----------------
// w_r1 [9][64][3][3] f32 -> wb3 [9 tap][8 q][16 n][8 e] bf16
__global__ __launch_bounds__(256) void wprep3(
    const float* __restrict__ w, unsigned short* __restrict__ wb3)
{
    int i = blockIdx.x * 256 + threadIdx.x;   // 9216
    if (i >= 9216) return;
    int tap = i >> 10;
    int q = (i >> 7) & 7;
    int n = (i >> 3) & 15;
    int e = i & 7;
    int c = q * 8 + e;
    int di = tap / 3, dj = tap % 3;
    float v = (n < KK) ? w[((n * C_ + c) * 3 + di) * 3 + dj] : 0.f;
    wb3[i] = f2bf(v);
}

// ---------------- Kernel C: conv5 + tanh via bf16 MFMA ----------------
#define PADC 72
__global__ __launch_bounds__(256) void conv5_mfma(
    const unsigned short* __restrict__ xh,   // [B][H][W][64] bf16
    const unsigned short* __restrict__ wb,   // [25][8][16][8] bf16
    const float* __restrict__ bias,
    float* __restrict__ out)                 // [B][9][H][W] f32 (tanh)
{
    __shared__ unsigned short xs[20 * 20 * PADC];

    int tid = threadIdx.x;
    int bx = blockIdx.x & 15;
    int by = (blockIdx.x >> 4) & 15;
    int b  = blockIdx.x >> 8;
    int h0 = by * 16, w0 = bx * 16;

    for (int q = tid; q < 400 * 8; q += 256) {
        int p = q & 7;
        int pix = q >> 3;
        int py = pix / 20, px = pix % 20;
        int gy = h0 + py - 2, gx = w0 + px - 2;
        short8 v = (short8)0;
        if (gy >= 0 && gy < H_ && gx >= 0 && gx < W_)
            v = *(const short8*)(xh + ((size_t)((b * 256 + gy) * 256 + gx) * 64 + p * 8));
        *(short8*)(&xs[pix * PADC + p * 8]) = v;
    }
    __syncthreads();

    int lane = tid & 63;
    int wid  = tid >> 6;
    int m16  = lane & 15;
    int lq   = lane >> 4;

    float4_ acc[4];
    float bj = (m16 < KK) ? bias[m16] : 0.f;
    #pragma unroll
    for (int r = 0; r < 4; ++r) acc[r] = (float4_){bj, bj, bj, bj};

    #pragma unroll
    for (int di = 0; di < 5; ++di) {
        #pragma unroll
        for (int dj = 0; dj < 5; ++dj) {
            int tap = di * 5 + dj;
            short8 bf0 = *(const short8*)(wb + (((tap * 8 + lq) * 16 + m16) * 8));
            short8 bf1 = *(const short8*)(wb + (((tap * 8 + 4 + lq) * 16 + m16) * 8));
            #pragma unroll
            for (int r = 0; r < 4; ++r) {
                int py = wid * 4 + r + di;
                int px = m16 + dj;
                const unsigned short* base = &xs[(py * 20 + px) * PADC + lq * 8];
                short8 a0 = *(const short8*)(base);
                short8 a1 = *(const short8*)(base + 32);
                acc[r] = __builtin_amdgcn_mfma_f32_16x16x32_bf16(a0, bf0, acc[r], 0, 0, 0);
                acc[r] = __builtin_amdgcn_mfma_f32_16x16x32_bf16(a1, bf1, acc[r], 0, 0, 0);
            }
        }
    }

    if (m16 < KK) {
        #pragma unroll
        for (int r = 0; r < 4; ++r) {
            int py = h0 + wid * 4 + r;
            #pragma unroll
            for (int reg = 0; reg < 4; ++reg) {
                int px = w0 + lq * 4 + reg;
                out[((b * KK + m16) * H_ + py) * W_ + px] = tanhf(acc[r][reg]);
            }
        }
    }
}

// ---------------- Kernel D: per-pixel 3x3 dynamic filter (NHWC), fused d = x - attf ----------------
// Writes attf (NCHW f32, output) and d (NHWC bf16, for conv3_mfma).
__global__ __launch_bounds__(256) void perpix_nhwc(
    const unsigned short* __restrict__ xh, const float* __restrict__ att,
    float* __restrict__ attf, unsigned short* __restrict__ dh)
{
    int t = blockIdx.x * 256 + threadIdx.x;   // 2097152
    int g = t & 7;
    int pix = t >> 3;
    int b = pix >> 16;
    int hw = pix & 65535;
    int h = hw >> 8, w = hw & 255;

    float a[KK];
    #pragma unroll
    for (int j = 0; j < KK; ++j)
        a[j] = att[((size_t)(b * KK + j) << 16) | hw];

    float s[8] = {0, 0, 0, 0, 0, 0, 0, 0};
    float xc[8] = {0, 0, 0, 0, 0, 0, 0, 0};
    #pragma unroll
    for (int di = 0; di < 3; ++di) {
        int y = h + di - 1;
        #pragma unroll
        for (int dj = 0; dj < 3; ++dj) {
            int xq = w + dj - 1;
            if (y < 0 || y >= H_ || xq < 0 || xq >= W_) continue;
            short8 v = *(const short8*)(xh + ((size_t)((b << 16) | (y << 8) | xq) * 64 + g * 8));
            float aj = a[di * 3 + dj];
            #pragma unroll
            for (int i = 0; i < 8; ++i) {
                float xv = bf2f(v[i]);
                s[i] += xv * aj;
                if (di == 1 && dj == 1) xc[i] = xv;
            }
        }
    }

    #pragma unroll
    for (int i = 0; i < 8; ++i)
        attf[((size_t)(b * C_ + g * 8 + i) << 16) | hw] = s[i];

    short8 dv;
    #pragma unroll
    for (int i = 0; i < 8; ++i) dv[i] = (short)f2bf(xc[i] - s[i]);
    *(short8*)(dh + (size_t)pix * 64 + g * 8) = dv;
}

// ---------------- Kernel E: conv3 (64 -> 9) on d via bf16 MFMA, + bias, no tanh ----------------
__global__ __launch_bounds__(256) void conv3_mfma(
    const unsigned short* __restrict__ dh,   // [B][H][W][64] bf16
    const unsigned short* __restrict__ wb3,  // [9][8][16][8] bf16
    const float* __restrict__ bias,
    float* __restrict__ out)                 // [B][9][H][W] f32
{
    __shared__ unsigned short xs[18 * 18 * PADC];  // 46656 B

    int tid = threadIdx.x;
    int bx = blockIdx.x & 15;
    int by = (blockIdx.x >> 4) & 15;
    int b  = blockIdx.x >> 8;
    int h0 = by * 16, w0 = bx * 16;

    for (int q = tid; q < 324 * 8; q += 256) {
        int p = q & 7;
        int pix = q >> 3;
        int py = pix / 18, px = pix % 18;
        int gy = h0 + py - 1, gx = w0 + px - 1;
        short8 v = (short8)0;
        if (gy >= 0 && gy < H_ && gx >= 0 && gx < W_)
            v = *(const short8*)(dh + ((size_t)((b * 256 + gy) * 256 + gx) * 64 + p * 8));
        *(short8*)(&xs[pix * PADC + p * 8]) = v;
    }
    __syncthreads();

    int lane = tid & 63;
    int wid  = tid >> 6;
    int m16  = lane & 15;
    int lq   = lane >> 4;

    float4_ acc[4];
    float bj = (m16 < KK) ? bias[m16] : 0.f;
    #pragma unroll
    for (int r = 0; r < 4; ++r) acc[r] = (float4_){bj, bj, bj, bj};

    #pragma unroll
    for (int di = 0; di < 3; ++di) {
        #pragma unroll
        for (int dj = 0; dj < 3; ++dj) {
            int tap = di * 3 + dj;
            short8 bf0 = *(const short8*)(wb3 + (((tap * 8 + lq) * 16 + m16) * 8));
            short8 bf1 = *(const short8*)(wb3 + (((tap * 8 + 4 + lq) * 16 + m16) * 8));
            #pragma unroll
            for (int r = 0; r < 4; ++r) {
                int py = wid * 4 + r + di;
                int px = m16 + dj;
                const unsigned short* base = &xs[(py * 18 + px) * PADC + lq * 8];
                short8 a0 = *(const short8*)(base);
                short8 a1 = *(const short8*)(base + 32);
                acc[r] = __builtin_amdgcn_mfma_f32_16x16x32_bf16(a0, bf0, acc[r], 0, 0, 0);
                acc[r] = __builtin_amdgcn_mfma_f32_16x16x32_bf16(a1, bf1, acc[r], 0, 0, 0);
            }
        }
    }

    if (m16 < KK) {
        #pragma unroll
        for (int r = 0; r < 4; ++r) {
            int py = h0 + wid * 4 + r;
            #pragma unroll
            for (int reg = 0; reg < 4; ++reg) {
                int px = w0 + lq * 4 + reg;
                out[((b * KK + m16) * H_ + py) * W_ + px] = acc[r][reg];
            }
        }
    }
}

// ---------------- Kernel F: 3x3 conv (9 -> 9), pad=1, + bias, tanh (LDS-staged) ----------------
__global__ __launch_bounds__(256) void conv3_tanh9(
    const float* __restrict__ r1, const float* __restrict__ w,
    const float* __restrict__ bias, float* __restrict__ out)
{
    const int TW = 32, TH = 8, PW = 34, PH = 10;
    __shared__ float lds[KK][PH][PW];  // 12240 B

    int tid = threadIdx.x;
    int tx = tid & 31, ty = tid >> 5;
    int bw = blockIdx.x & 7;
    int bh = (blockIdx.x >> 3) & 31;
    int b  = blockIdx.x >> 8;
    int h0 = bh * TH, w0 = bw * TW;

    for (int idx = tid; idx < KK * PH * PW; idx += 256) {
        int px = idx % PW;
        int py = (idx / PW) % PH;
        int ch = idx / (PW * PH);
        int gy = h0 + py - 1, gx = w0 + px - 1;
        float v = 0.f;
        if (gy >= 0 && gy < H_ && gx >= 0 && gx < W_)
            v = r1[((b * KK + ch) * H_ + gy) * W_ + gx];
        lds[ch][py][px] = v;
    }
    __syncthreads();

    float acc[KK];
    #pragma unroll
    for (int j = 0; j < KK; ++j) acc[j] = bias[j];

    for (int cin = 0; cin < KK; ++cin) {
        #pragma unroll
        for (int di = 0; di < 3; ++di) {
            #pragma unroll
            for (int dj = 0; dj < 3; ++dj) {
                float xv = lds[cin][ty + di][tx + dj];
                #pragma unroll
                for (int j = 0; j < KK; ++j)
                    acc[j] += xv * w[((j * KK + cin) * 3 + di) * 3 + dj];
            }
        }
    }

    int h = h0 + ty, wq = w0 + tx;
    #pragma unroll
    for (int j = 0; j < KK; ++j)
        out[((b * KK + j) * H_ + h) * W_ + wq] = tanhf(acc[j]);
}

extern "C" void kernel_launch(void* const* d_in, const int* in_sizes, int n_in,
                              void* d_out, int out_size, void* d_ws, size_t ws_size,
                              hipStream_t stream) {
    const float* feature = (const float*)d_in[0];
    const float* w_sharp = (const float*)d_in[1];
    const float* b_sharp = (const float*)d_in[2];
    const float* w_r1    = (const float*)d_in[3];
    const float* b_r1    = (const float*)d_in[4];
    const float* w_r2    = (const float*)d_in[5];
    const float* b_r2    = (const float*)d_in[6];

    float* out_reblur = (float*)d_out;                          // [4,9,256,256]
    float* out_attf   = out_reblur + (size_t)B_ * KK * H_ * W_; // [4,64,256,256]

    char* ws = (char*)d_ws;
    unsigned short* xh  = (unsigned short*)ws;                   // 33554432 B
    unsigned short* dh  = (unsigned short*)(ws + 33554432);      // 33554432 B
    unsigned short* wb  = (unsigned short*)(ws + 67108864);      // 51200 -> pad 65536
    unsigned short* wb3 = (unsigned short*)(ws + 67174400);      // 18432 -> pad 32768
    float* ws_att = (float*)(ws + 67207168);                     // 9437184 B
    float* ws_r1  = ws_att;  // alias: att fully consumed by perpix_nhwc before conv3_mfma writes r1

    nchw2nhwc<<<8192, 256, 0, stream>>>(feature, xh);
    wprep<<<100, 256, 0, stream>>>(w_sharp, wb);
    wprep3<<<36, 256, 0, stream>>>(w_r1, wb3);
    conv5_mfma<<<1024, 256, 0, stream>>>(xh, wb, b_sharp, ws_att);
    perpix_nhwc<<<8192, 256, 0, stream>>>(xh, ws_att, out_attf, dh);
    conv3_mfma<<<1024, 256, 0, stream>>>(dh, wb3, b_r1, ws_r1);
    conv3_tanh9<<<1024, 256, 0, stream>>>(ws_r1, w_r2, b_r2, out_reblur);
}

// Round 4
// 127.221 us; speedup vs baseline: 3.3401x; 1.0672x over previous
//
#include <hip/hip_runtime.h>

#define B_ 4
#define C_ 64
#define H_ 256
#define W_ 256
#define KK 9

typedef __attribute__((ext_vector_type(8))) short short8;
typedef __attribute__((ext_vector_type(4))) float float4_;

static __device__ __forceinline__ unsigned short f2bf(float f) {
    unsigned int u = __builtin_bit_cast(unsigned int, f);
    unsigned int r = (u + 0x7fffu + ((u >> 16) & 1u)) >> 16;  // RNE
    return (unsigned short)r;
}
static __device__ __forceinline__ float bf2f(short s) {
    return __builtin_bit_cast(float, (unsigned int)((unsigned short)s) << 16);
}

// ---------------- Kernel A: NCHW fp32 -> NHWC bf16 (LDS transpose) ----------------
// One block per image row (256 pixels). Phase 1: coalesced f32 reads, bf16 into
// LDS [pix][66]. Phase 2: short8 LDS reads -> fully coalesced 16B global writes.
__global__ __launch_bounds__(256) void nchw2nhwc(
    const float* __restrict__ x, unsigned short* __restrict__ xh)
{
    __shared__ unsigned short t[256 * 66];  // 33792 B
    int row = blockIdx.x;                   // b*256 + h
    int b = row >> 8;
    const float* src = x + ((size_t)b * 64) * 65536 + (size_t)(row & 255) * 256;
    int tid = threadIdx.x;

    #pragma unroll 4
    for (int c = 0; c < 64; ++c)
        t[tid * 66 + c] = f2bf(src[(size_t)c * 65536 + tid]);
    __syncthreads();

    unsigned short* dst = xh + (size_t)row * 256 * 64;
    #pragma unroll
    for (int it = 0; it < 8; ++it) {
        int idx = it * 256 + tid;
        int pix = idx >> 3, g = idx & 7;
        short8 v = *(const short8*)(&t[pix * 66 + g * 8]);
        *(short8*)(dst + (size_t)pix * 64 + g * 8) = v;
    }
}

// ---------------- Kernel B: 5x5 weight transform ----------------
// w_sharp [9][64][5][5] f32 -> wb [25 tap][8 q][16 n][8 e] bf16 (c = q*8+e)
__global__ __launch_bounds__(256) void wprep(
    const float* __restrict__ w, unsigned short* __restrict__ wb)
{
    int i = blockIdx.x * 256 + threadIdx.x;   // 25600
    if (i >= 25600) return;
    int tap = i >> 10;
    int q = (i >> 7) & 7;
    int n = (i >> 3) & 15;
    int e = i & 7;
    int c = q * 8 + e;
    int di = tap / 5, dj = tap % 5;
    float v = (n < KK) ? w[((n * C_ + c) * 5 + di) * 5 + dj] : 0.f;
    wb[i] = f2bf(v);
}

// ---------------- Kernel B2: 3x3 weight transform ----------------
__global__ __launch_bounds__(256) void wprep3(
    const float* __restrict__ w, unsigned short* __restrict__ wb3)
{
    int i = blockIdx.x * 256 + threadIdx.x;   // 9216
    if (i >= 9216) return;
    int tap = i >> 10;
    int q = (i >> 7) & 7;
    int n = (i >> 3) & 15;
    int e = i & 7;
    int c = q * 8 + e;
    int di = tap / 3, dj = tap % 3;
    float v = (n < KK) ? w[((n * C_ + c) * 3 + di) * 3 + dj] : 0.f;
    wb3[i] = f2bf(v);
}

// ---------------- Kernel C: conv5 + tanh via bf16 MFMA ----------------
// Restructured tap loop: rows with equal s = r + di share one A-fragment
// (80 ds_read_b128/wave instead of 200).
#define PADC 72
__global__ __launch_bounds__(256) void conv5_mfma(
    const unsigned short* __restrict__ xh,   // [B][H][W][64] bf16
    const unsigned short* __restrict__ wb,   // [25][8][16][8] bf16
    const float* __restrict__ bias,
    float* __restrict__ out)                 // [B][9][H][W] f32 (tanh)
{
    __shared__ unsigned short xs[20 * 20 * PADC];

    int tid = threadIdx.x;
    int bx = blockIdx.x & 15;
    int by = (blockIdx.x >> 4) & 15;
    int b  = blockIdx.x >> 8;
    int h0 = by * 16, w0 = bx * 16;

    for (int q = tid; q < 400 * 8; q += 256) {
        int p = q & 7;
        int pix = q >> 3;
        int py = pix / 20, px = pix % 20;
        int gy = h0 + py - 2, gx = w0 + px - 2;
        short8 v = (short8)0;
        if (gy >= 0 && gy < H_ && gx >= 0 && gx < W_)
            v = *(const short8*)(xh + ((size_t)((b * 256 + gy) * 256 + gx) * 64 + p * 8));
        *(short8*)(&xs[pix * PADC + p * 8]) = v;
    }
    __syncthreads();

    int lane = tid & 63;
    int wid  = tid >> 6;
    int m16  = lane & 15;
    int lq   = lane >> 4;

    float4_ acc[4];
    float bj = (m16 < KK) ? bias[m16] : 0.f;
    #pragma unroll
    for (int r = 0; r < 4; ++r) acc[r] = (float4_){bj, bj, bj, bj};

    #pragma unroll
    for (int dj = 0; dj < 5; ++dj) {
        short8 bfr[5][2];
        #pragma unroll
        for (int di = 0; di < 5; ++di) {
            int tap = di * 5 + dj;
            bfr[di][0] = *(const short8*)(wb + (((tap * 8 + lq) * 16 + m16) * 8));
            bfr[di][1] = *(const short8*)(wb + (((tap * 8 + 4 + lq) * 16 + m16) * 8));
        }
        int px = m16 + dj;
        #pragma unroll
        for (int s = 0; s < 8; ++s) {
            const unsigned short* base = &xs[((wid * 4 + s) * 20 + px) * PADC + lq * 8];
            short8 a0 = *(const short8*)(base);
            short8 a1 = *(const short8*)(base + 32);
            #pragma unroll
            for (int di = 0; di < 5; ++di) {
                int r = s - di;
                if (r < 0 || r > 3) continue;
                acc[r] = __builtin_amdgcn_mfma_f32_16x16x32_bf16(a0, bfr[di][0], acc[r], 0, 0, 0);
                acc[r] = __builtin_amdgcn_mfma_f32_16x16x32_bf16(a1, bfr[di][1], acc[r], 0, 0, 0);
            }
        }
    }

    if (m16 < KK) {
        #pragma unroll
        for (int r = 0; r < 4; ++r) {
            int py = h0 + wid * 4 + r;
            #pragma unroll
            for (int reg = 0; reg < 4; ++reg) {
                int px = w0 + lq * 4 + reg;
                out[((b * KK + m16) * H_ + py) * W_ + px] = tanhf(acc[r][reg]);
            }
        }
    }
}

// ---------------- Kernel D: per-pixel 3x3 dynamic filter (NHWC), fused d = x - attf ----------------
__global__ __launch_bounds__(256) void perpix_nhwc(
    const unsigned short* __restrict__ xh, const float* __restrict__ att,
    float* __restrict__ attf, unsigned short* __restrict__ dh)
{
    int t = blockIdx.x * 256 + threadIdx.x;   // 2097152
    int g = t & 7;
    int pix = t >> 3;
    int b = pix >> 16;
    int hw = pix & 65535;
    int h = hw >> 8, w = hw & 255;

    float a[KK];
    #pragma unroll
    for (int j = 0; j < KK; ++j)
        a[j] = att[((size_t)(b * KK + j) << 16) | hw];

    float s[8] = {0, 0, 0, 0, 0, 0, 0, 0};
    float xc[8] = {0, 0, 0, 0, 0, 0, 0, 0};
    #pragma unroll
    for (int di = 0; di < 3; ++di) {
        int y = h + di - 1;
        #pragma unroll
        for (int dj = 0; dj < 3; ++dj) {
            int xq = w + dj - 1;
            if (y < 0 || y >= H_ || xq < 0 || xq >= W_) continue;
            short8 v = *(const short8*)(xh + ((size_t)((b << 16) | (y << 8) | xq) * 64 + g * 8));
            float aj = a[di * 3 + dj];
            #pragma unroll
            for (int i = 0; i < 8; ++i) {
                float xv = bf2f(v[i]);
                s[i] += xv * aj;
                if (di == 1 && dj == 1) xc[i] = xv;
            }
        }
    }

    #pragma unroll
    for (int i = 0; i < 8; ++i)
        attf[((size_t)(b * C_ + g * 8 + i) << 16) | hw] = s[i];

    short8 dv;
    #pragma unroll
    for (int i = 0; i < 8; ++i) dv[i] = (short)f2bf(xc[i] - s[i]);
    *(short8*)(dh + (size_t)pix * 64 + g * 8) = dv;
}

// ---------------- Kernel E: conv3 (64 -> 9) on d via bf16 MFMA ----------------
__global__ __launch_bounds__(256) void conv3_mfma(
    const unsigned short* __restrict__ dh,   // [B][H][W][64] bf16
    const unsigned short* __restrict__ wb3,  // [9][8][16][8] bf16
    const float* __restrict__ bias,
    float* __restrict__ out)                 // [B][9][H][W] f32
{
    __shared__ unsigned short xs[18 * 18 * PADC];

    int tid = threadIdx.x;
    int bx = blockIdx.x & 15;
    int by = (blockIdx.x >> 4) & 15;
    int b  = blockIdx.x >> 8;
    int h0 = by * 16, w0 = bx * 16;

    for (int q = tid; q < 324 * 8; q += 256) {
        int p = q & 7;
        int pix = q >> 3;
        int py = pix / 18, px = pix % 18;
        int gy = h0 + py - 1, gx = w0 + px - 1;
        short8 v = (short8)0;
        if (gy >= 0 && gy < H_ && gx >= 0 && gx < W_)
            v = *(const short8*)(dh + ((size_t)((b * 256 + gy) * 256 + gx) * 64 + p * 8));
        *(short8*)(&xs[pix * PADC + p * 8]) = v;
    }
    __syncthreads();

    int lane = tid & 63;
    int wid  = tid >> 6;
    int m16  = lane & 15;
    int lq   = lane >> 4;

    float4_ acc[4];
    float bj = (m16 < KK) ? bias[m16] : 0.f;
    #pragma unroll
    for (int r = 0; r < 4; ++r) acc[r] = (float4_){bj, bj, bj, bj};

    #pragma unroll
    for (int dj = 0; dj < 3; ++dj) {
        short8 bfr[3][2];
        #pragma unroll
        for (int di = 0; di < 3; ++di) {
            int tap = di * 3 + dj;
            bfr[di][0] = *(const short8*)(wb3 + (((tap * 8 + lq) * 16 + m16) * 8));
            bfr[di][1] = *(const short8*)(wb3 + (((tap * 8 + 4 + lq) * 16 + m16) * 8));
        }
        int px = m16 + dj;
        #pragma unroll
        for (int s = 0; s < 6; ++s) {
            const unsigned short* base = &xs[((wid * 4 + s) * 18 + px) * PADC + lq * 8];
            short8 a0 = *(const short8*)(base);
            short8 a1 = *(const short8*)(base + 32);
            #pragma unroll
            for (int di = 0; di < 3; ++di) {
                int r = s - di;
                if (r < 0 || r > 3) continue;
                acc[r] = __builtin_amdgcn_mfma_f32_16x16x32_bf16(a0, bfr[di][0], acc[r], 0, 0, 0);
                acc[r] = __builtin_amdgcn_mfma_f32_16x16x32_bf16(a1, bfr[di][1], acc[r], 0, 0, 0);
            }
        }
    }

    if (m16 < KK) {
        #pragma unroll
        for (int r = 0; r < 4; ++r) {
            int py = h0 + wid * 4 + r;
            #pragma unroll
            for (int reg = 0; reg < 4; ++reg) {
                int px = w0 + lq * 4 + reg;
                out[((b * KK + m16) * H_ + py) * W_ + px] = acc[r][reg];
            }
        }
    }
}

// ---------------- Kernel F: 3x3 conv (9 -> 9), pad=1, + bias, tanh ----------------
__global__ __launch_bounds__(256) void conv3_tanh9(
    const float* __restrict__ r1, const float* __restrict__ w,
    const float* __restrict__ bias, float* __restrict__ out)
{
    const int TW = 32, TH = 8, PW = 34, PH = 10;
    __shared__ float lds[KK][PH][PW];

    int tid = threadIdx.x;
    int tx = tid & 31, ty = tid >> 5;
    int bw = blockIdx.x & 7;
    int bh = (blockIdx.x >> 3) & 31;
    int b  = blockIdx.x >> 8;
    int h0 = bh * TH, w0 = bw * TW;

    for (int idx = tid; idx < KK * PH * PW; idx += 256) {
        int px = idx % PW;
        int py = (idx / PW) % PH;
        int ch = idx / (PW * PH);
        int gy = h0 + py - 1, gx = w0 + px - 1;
        float v = 0.f;
        if (gy >= 0 && gy < H_ && gx >= 0 && gx < W_)
            v = r1[((b * KK + ch) * H_ + gy) * W_ + gx];
        lds[ch][py][px] = v;
    }
    __syncthreads();

    float acc[KK];
    #pragma unroll
    for (int j = 0; j < KK; ++j) acc[j] = bias[j];

    for (int cin = 0; cin < KK; ++cin) {
        #pragma unroll
        for (int di = 0; di < 3; ++di) {
            #pragma unroll
            for (int dj = 0; dj < 3; ++dj) {
                float xv = lds[cin][ty + di][tx + dj];
                #pragma unroll
                for (int j = 0; j < KK; ++j)
                    acc[j] += xv * w[((j * KK + cin) * 3 + di) * 3 + dj];
            }
        }
    }

    int h = h0 + ty, wq = w0 + tx;
    #pragma unroll
    for (int j = 0; j < KK; ++j)
        out[((b * KK + j) * H_ + h) * W_ + wq] = tanhf(acc[j]);
}

extern "C" void kernel_launch(void* const* d_in, const int* in_sizes, int n_in,
                              void* d_out, int out_size, void* d_ws, size_t ws_size,
                              hipStream_t stream) {
    const float* feature = (const float*)d_in[0];
    const float* w_sharp = (const float*)d_in[1];
    const float* b_sharp = (const float*)d_in[2];
    const float* w_r1    = (const float*)d_in[3];
    const float* b_r1    = (const float*)d_in[4];
    const float* w_r2    = (const float*)d_in[5];
    const float* b_r2    = (const float*)d_in[6];

    float* out_reblur = (float*)d_out;                          // [4,9,256,256]
    float* out_attf   = out_reblur + (size_t)B_ * KK * H_ * W_; // [4,64,256,256]

    char* ws = (char*)d_ws;
    unsigned short* xh  = (unsigned short*)ws;                   // 33554432 B
    unsigned short* dh  = (unsigned short*)(ws + 33554432);      // 33554432 B
    unsigned short* wb  = (unsigned short*)(ws + 67108864);      // 51200 -> pad 65536
    unsigned short* wb3 = (unsigned short*)(ws + 67174400);      // 18432 -> pad 32768
    float* ws_att = (float*)(ws + 67207168);                     // 9437184 B
    float* ws_r1  = ws_att;  // alias: att fully consumed before conv3_mfma writes r1

    nchw2nhwc<<<1024, 256, 0, stream>>>(feature, xh);
    wprep<<<100, 256, 0, stream>>>(w_sharp, wb);
    wprep3<<<36, 256, 0, stream>>>(w_r1, wb3);
    conv5_mfma<<<1024, 256, 0, stream>>>(xh, wb, b_sharp, ws_att);
    perpix_nhwc<<<8192, 256, 0, stream>>>(xh, ws_att, out_attf, dh);
    conv3_mfma<<<1024, 256, 0, stream>>>(dh, wb3, b_r1, ws_r1);
    conv3_tanh9<<<1024, 256, 0, stream>>>(ws_r1, w_r2, b_r2, out_reblur);
}